// Round 13
// baseline (2693.030 us; speedup 1.0000x reference)
//
#include <hip/hip_runtime.h>
#include <math.h>

#define B 64
#define N 196
#define E 2048
#define D 512
#define AA 512
#define EM 512
#define V 10000
#define TSTEPS 20
#define XC 3072          // xcat: [inp(512) | awe(2048) | h(512)] contiguous
#define HOFF 2560        // h slot offset in xcat
#define AGW 2560         // ag row: [att2(512) | gate(2048)]
#define AGS 4            // split-K slices for att2|gate
#define ZS1 8            // split-K slices for W_ih
#define ZS2 4            // split-K slices for W_hh
#define PS 2             // split-K slices for preds
#define ATT1_ELEMS ((size_t)B * N * AA)   // 6422528
#define M_ROWS (B * N)                    // 12544

typedef _Float16 f16x4 __attribute__((ext_vector_type(4)));
typedef float f32x4v __attribute__((ext_vector_type(4)));

__device__ __forceinline__ float sigmoidf_(float x) { return 1.0f / (1.0f + expf(-x)); }

__device__ __forceinline__ float4 ldg4_guard(const float* __restrict__ wp, int n, int Nn) {
    if (n + 3 < Nn) return *(const float4*)&wp[n];
    float4 bv;
    bv.x = (n     < Nn) ? wp[n]     : 0.f;
    bv.y = (n + 1 < Nn) ? wp[n + 1] : 0.f;
    bv.z = (n + 2 < Nn) ? wp[n + 2] : 0.f;
    bv.w = (n + 3 < Nn) ? wp[n + 3] : 0.f;
    return bv;
}

__device__ __forceinline__ void split4(float4 v, f16x4& h, f16x4& lo) {
    h[0] = (_Float16)v.x; lo[0] = (_Float16)(v.x - (float)h[0]);
    h[1] = (_Float16)v.y; lo[1] = (_Float16)(v.y - (float)h[1]);
    h[2] = (_Float16)v.z; lo[2] = (_Float16)(v.z - (float)h[2]);
    h[3] = (_Float16)v.w; lo[3] = (_Float16)(v.w - (float)h[3]);
}

// ---------------- mean over N ----------------
__global__ __launch_bounds__(256) void k_mean(const float* __restrict__ feat,
                                              float* __restrict__ mean_enc) {
    int i = blockIdx.x * 256 + threadIdx.x;
    int b = i >> 11, e = i & (E - 1);
    const float* p = feat + (size_t)b * N * E + e;
    float s = 0.f;
    for (int n = 0; n < N; ++n) s += p[(size_t)n * E];
    mean_enc[i] = s * (1.0f / (float)N);
}

// ---------------- h,c init; h written into xcat h-slot ----------------
__global__ __launch_bounds__(256) void k_init_hc(const float* __restrict__ me,
                                                 const float* __restrict__ Wh, const float* __restrict__ bh,
                                                 const float* __restrict__ Wc, const float* __restrict__ bc,
                                                 float* __restrict__ xcat, float* __restrict__ c) {
    int i = blockIdx.x * 256 + threadIdx.x;
    int b = i >> 9, d = i & (D - 1);
    const float* m = me + (size_t)b * E;
    float ha = bh[d], ca = bc[d];
    for (int e = 0; e < E; ++e) {
        float mv = m[e];
        ha += mv * Wh[(size_t)e * D + d];
        ca += mv * Wc[(size_t)e * D + d];
    }
    xcat[(size_t)b * XC + HOFF + d] = ha;
    c[i] = ca;
}

// ---------------- inp = embedding[1] into xcat ----------------
__global__ __launch_bounds__(256) void k_init_inp(const float* __restrict__ emb,
                                                  float* __restrict__ xcat) {
    int i = blockIdx.x * 256 + threadIdx.x;   // 32768
    int b = i >> 9, k = i & (EM - 1);
    xcat[(size_t)b * XC + k] = emb[EM + k];
}

// ---------------- pack W_enc_att -> transposed f16 hi/lo: Bt[n][k] ----------------
__global__ __launch_bounds__(256) void k_packB(const float* __restrict__ Wea,
                                               _Float16* __restrict__ Bth,
                                               _Float16* __restrict__ Btl) {
    int i = blockIdx.x * 256 + threadIdx.x;   // over 512*2048
    int n = i >> 11, k = i & (E - 1);
    float v = Wea[(size_t)k * AA + n];
    _Float16 h = (_Float16)v;
    Bth[i] = h;
    Btl[i] = (_Float16)(v - (float)h);
}

// ---------------- pack feat -> f16 hi/lo: Ah/Al [12544][2048] ----------------
__global__ __launch_bounds__(256) void k_packA(const float* __restrict__ feat,
                                               _Float16* __restrict__ Ah,
                                               _Float16* __restrict__ Al) {
    size_t i = ((size_t)blockIdx.x * 256 + threadIdx.x) * 4;   // 25,690,112 elems
    float4 v = *(const float4*)&feat[i];
    f16x4 h, lo;
    split4(v, h, lo);
    *(f16x4*)&Ah[i] = h;
    *(f16x4*)&Al[i] = lo;
}

// ---------------- att1 via MFMA f16 hi/lo: C = Ahi*Bhi + Ahi*Blo + Alo*Bhi ------------
// Layouts HW-verified r12 (absmax 0). Grid 784 1-D, chunked XCD swizzle so the 4 col-tile
// siblings of one A-row-tile run on one XCD (A L2-reuse). Register prefetch of next k-tile.
// PACKED=1: A from pre-split f16 (no conversion VALU); PACKED=0: on-the-fly split.
template<int PACKED>
__global__ __launch_bounds__(256) void k_att1_mfma(const float* __restrict__ Af,
                                                   const _Float16* __restrict__ Ah,
                                                   const _Float16* __restrict__ Al,
                                                   const _Float16* __restrict__ Bth,
                                                   const _Float16* __restrict__ Btl,
                                                   float* __restrict__ Cm) {
    int bid = blockIdx.x;                  // 784 = 8 XCD chunks x 98
    int wg = (bid & 7) * 98 + (bid >> 3);  // bijective (784 % 8 == 0)
    int xt = wg >> 2, yc = wg & 3;         // xt: A-row-tile 0..195, yc: col-tile 0..3
    int w = threadIdx.x >> 6, l = threadIdx.x & 63;
    int wr = w >> 1, wc = w & 1;
    int row0 = xt * 64 + wr * 32;
    int col0 = yc * 128 + wc * 64;
    int lr = l & 15, lk = l >> 4;
    int ka0 = 4 * lk;
    f32x4v acc[2][4] = {};
    const _Float16* bhp = Bth + (size_t)(col0 + lr) * E + ka0;
    const _Float16* blp = Btl + (size_t)(col0 + lr) * E + ka0;
    const float* af0 = Af + (size_t)(row0 + lr) * E + ka0;
    const float* af1 = Af + (size_t)(row0 + 16 + lr) * E + ka0;
    const _Float16* ah0p = Ah + (size_t)(row0 + lr) * E + ka0;
    const _Float16* al0p = Al + (size_t)(row0 + lr) * E + ka0;
    const _Float16* ah1p = Ah + (size_t)(row0 + 16 + lr) * E + ka0;
    const _Float16* al1p = Al + (size_t)(row0 + 16 + lr) * E + ka0;

    f16x4 ah0, al0, ah1, al1, bh[4], bl[4];
    f16x4 nah0, nal0, nah1, nal1, nbh[4], nbl[4];

#define LOAD_A(k0, H0, L0, H1, L1)                                     \
    if (PACKED) {                                                      \
        H0 = *(const f16x4*)(ah0p + (k0));  L0 = *(const f16x4*)(al0p + (k0)); \
        H1 = *(const f16x4*)(ah1p + (k0));  L1 = *(const f16x4*)(al1p + (k0)); \
    } else {                                                           \
        split4(*(const float4*)(af0 + (k0)), H0, L0);                  \
        split4(*(const float4*)(af1 + (k0)), H1, L1);                  \
    }
#define LOAD_B(k0, BH, BL)                                             \
    _Pragma("unroll")                                                  \
    for (int ni = 0; ni < 4; ++ni) {                                   \
        BH[ni] = *(const f16x4*)(bhp + (size_t)ni * 16 * E + (k0));    \
        BL[ni] = *(const f16x4*)(blp + (size_t)ni * 16 * E + (k0));    \
    }

    LOAD_A(0, ah0, al0, ah1, al1)
    LOAD_B(0, bh, bl)
    for (int k0 = 0; k0 < E; k0 += 16) {
        if (k0 + 16 < E) {                 // prefetch next k-tile before the MFMA block
            LOAD_A(k0 + 16, nah0, nal0, nah1, nal1)
            LOAD_B(k0 + 16, nbh, nbl)
        }
#pragma unroll
        for (int ni = 0; ni < 4; ++ni) {
            acc[0][ni] = __builtin_amdgcn_mfma_f32_16x16x16f16(ah0, bh[ni], acc[0][ni], 0, 0, 0);
            acc[0][ni] = __builtin_amdgcn_mfma_f32_16x16x16f16(ah0, bl[ni], acc[0][ni], 0, 0, 0);
            acc[0][ni] = __builtin_amdgcn_mfma_f32_16x16x16f16(al0, bh[ni], acc[0][ni], 0, 0, 0);
            acc[1][ni] = __builtin_amdgcn_mfma_f32_16x16x16f16(ah1, bh[ni], acc[1][ni], 0, 0, 0);
            acc[1][ni] = __builtin_amdgcn_mfma_f32_16x16x16f16(ah1, bl[ni], acc[1][ni], 0, 0, 0);
            acc[1][ni] = __builtin_amdgcn_mfma_f32_16x16x16f16(al1, bh[ni], acc[1][ni], 0, 0, 0);
        }
        ah0 = nah0; al0 = nal0; ah1 = nah1; al1 = nal1;
#pragma unroll
        for (int ni = 0; ni < 4; ++ni) { bh[ni] = nbh[ni]; bl[ni] = nbl[ni]; }
    }
#undef LOAD_A
#undef LOAD_B
#pragma unroll
    for (int mi = 0; mi < 2; ++mi)
#pragma unroll
        for (int ni = 0; ni < 4; ++ni)
#pragma unroll
            for (int r = 0; r < 4; ++r)
                Cm[(size_t)(row0 + 16 * mi + lk * 4 + r) * AA + col0 + 16 * ni + lr] = acc[mi][ni][r];
}

// ---------------- att2|gate split-K: agp[sl][b][2560] (register-prefetched) ----------------
__global__ __launch_bounds__(256) void k_ag(const float* __restrict__ xcat,
                                            const float* __restrict__ Wda,
                                            const float* __restrict__ Wfb,
                                            const float* __restrict__ bfb,
                                            float* __restrict__ agp) {
    __shared__ float As[16][68];
    __shared__ float Bs[16][64];
    int tile = blockIdx.x, slice = blockIdx.y;
    const float* W; const float* bias = nullptr; int ldw, n0, co;
    if (tile < 8) { W = Wda; ldw = AA; n0 = tile * 64;       co = n0; }
    else          { W = Wfb; ldw = E;  n0 = (tile - 8) * 64; co = AA + n0;
                    if (slice == 0) bias = bfb; }
    float* ag = agp + (size_t)slice * B * AGW;
    int kbeg = slice * (D / AGS), kend = kbeg + D / AGS;
    const float* A = xcat + HOFF;
    int t = threadIdx.x;
    int tx = t & 15, ty = t >> 4;
    int arow = t >> 2, ak4 = (t & 3) * 4;
    int bk = t >> 4, bc4 = (t & 15) * 4;
    float4 pav = *(const float4*)&A[(size_t)arow * XC + kbeg + ak4];
    float4 pbv = *(const float4*)&W[(size_t)(kbeg + bk) * ldw + n0 + bc4];
    float acc[4][4] = {};
    for (int k0 = kbeg; k0 < kend; k0 += 16) {
        As[ak4 + 0][arow] = pav.x; As[ak4 + 1][arow] = pav.y;
        As[ak4 + 2][arow] = pav.z; As[ak4 + 3][arow] = pav.w;
        *(float4*)&Bs[bk][bc4] = pbv;
        __syncthreads();
        if (k0 + 16 < kend) {
            pav = *(const float4*)&A[(size_t)arow * XC + k0 + 16 + ak4];
            pbv = *(const float4*)&W[(size_t)(k0 + 16 + bk) * ldw + n0 + bc4];
        }
#pragma unroll
        for (int kk = 0; kk < 16; ++kk) {
            float4 a4 = *(const float4*)&As[kk][ty * 4];
            float4 b4 = *(const float4*)&Bs[kk][tx * 4];
            acc[0][0] += a4.x * b4.x; acc[0][1] += a4.x * b4.y; acc[0][2] += a4.x * b4.z; acc[0][3] += a4.x * b4.w;
            acc[1][0] += a4.y * b4.x; acc[1][1] += a4.y * b4.y; acc[1][2] += a4.y * b4.z; acc[1][3] += a4.y * b4.w;
            acc[2][0] += a4.z * b4.x; acc[2][1] += a4.z * b4.y; acc[2][2] += a4.z * b4.z; acc[2][3] += a4.z * b4.w;
            acc[3][0] += a4.w * b4.x; acc[3][1] += a4.w * b4.y; acc[3][2] += a4.w * b4.z; acc[3][3] += a4.w * b4.w;
        }
        __syncthreads();
    }
#pragma unroll
    for (int i = 0; i < 4; ++i) {
        int row = ty * 4 + i;
#pragma unroll
        for (int j = 0; j < 4; ++j) {
            float v = acc[i][j];
            if (bias) v += bias[n0 + tx * 4 + j];
            ag[(size_t)row * AGW + co + tx * 4 + j] = v;
        }
    }
}

// ---------------- scores: wave per (b,n) row, float4; sums AGS att2 partials ----------------
__global__ __launch_bounds__(256) void k_scores(const float* __restrict__ att1,
                                                const float* __restrict__ agp,
                                                const float* __restrict__ wfull,
                                                float* __restrict__ scores) {
    int wid = threadIdx.x >> 6, lane = threadIdx.x & 63;
    int bn = blockIdx.x * 4 + wid;            // 12544 rows
    int b = bn / N;
    const float* a1 = att1 + (size_t)bn * AA;
    const float* a2 = agp + (size_t)b * AGW;
    const size_t SL = (size_t)B * AGW;
    float s = 0.f;
#pragma unroll
    for (int i = 0; i < AA / 256; ++i) {
        int a = i * 256 + lane * 4;
        float4 v  = *(const float4*)&a1[a];
        float4 p0 = *(const float4*)&a2[a];
        float4 p1 = *(const float4*)&a2[SL + a];
        float4 p2 = *(const float4*)&a2[2 * SL + a];
        float4 p3 = *(const float4*)&a2[3 * SL + a];
        float4 wf = *(const float4*)&wfull[a];
        s += fmaxf(v.x + p0.x + p1.x + p2.x + p3.x, 0.f) * wf.x;
        s += fmaxf(v.y + p0.y + p1.y + p2.y + p3.y, 0.f) * wf.y;
        s += fmaxf(v.z + p0.z + p1.z + p2.z + p3.z, 0.f) * wf.z;
        s += fmaxf(v.w + p0.w + p1.w + p2.w + p3.w, 0.f) * wf.w;
    }
    for (int off = 32; off; off >>= 1) s += __shfl_down(s, off);
    if (lane == 0) scores[bn] = s;
}

// ---------------- awe: in-block softmax + float2 weighted sum + gate ----------------
__global__ __launch_bounds__(256) void k_awe(const float* __restrict__ scores,
                                             const float* __restrict__ feat,
                                             const float* __restrict__ agp,
                                             float* __restrict__ xcat) {
    __shared__ float al[N];
    __shared__ float red[256];
    int b = blockIdx.y, ch = blockIdx.x, t = threadIdx.x;
    float v = (t < N) ? scores[b * N + t] : -INFINITY;
    red[t] = v; __syncthreads();
    for (int s = 128; s; s >>= 1) { if (t < s) red[t] = fmaxf(red[t], red[t + s]); __syncthreads(); }
    float mx = red[0]; __syncthreads();
    float e = (t < N) ? expf(v - mx) : 0.f;
    red[t] = e; __syncthreads();
    for (int s = 128; s; s >>= 1) { if (t < s) red[t] += red[t + s]; __syncthreads(); }
    float inv = 1.0f / red[0];
    if (t < N) al[t] = e * inv;
    __syncthreads();
    int e0 = ch * 512 + t * 2;
    const float* f = feat + (size_t)b * N * E + e0;
    float sx = 0.f, sy = 0.f;
    for (int n = 0; n < N; n += 2) {     // N even: no tail
        float a0 = al[n], a1v = al[n + 1];
        float2 f0 = *(const float2*)f;
        float2 f1 = *(const float2*)(f + E);
        sx += a0 * f0.x + a1v * f1.x;
        sy += a0 * f0.y + a1v * f1.y;
        f += (size_t)2 * E;
    }
    const float* gp = agp + (size_t)b * AGW + AA + e0;
    const size_t SL = (size_t)B * AGW;
    float2 g0 = *(const float2*)&gp[0];
    float2 g1 = *(const float2*)&gp[SL];
    float2 g2 = *(const float2*)&gp[2 * SL];
    float2 g3 = *(const float2*)&gp[3 * SL];
    float2 o;
    o.x = sx * sigmoidf_(g0.x + g1.x + g2.x + g3.x);
    o.y = sy * sigmoidf_(g0.y + g1.y + g2.y + g3.y);
    *(float2*)&xcat[(size_t)b * XC + EM + e0] = o;
}

// ---------------- z partials: one launch, 12 slices (8 ih + 4 hh), prefetched ----------------
__global__ __launch_bounds__(256) void k_z(const float* __restrict__ xcat,
                                           const float* __restrict__ Wih,
                                           const float* __restrict__ Whh,
                                           float* __restrict__ zpart) {
    __shared__ float As[16][68];
    __shared__ float Bs[16][64];
    int slice = blockIdx.y;
    const float* A; const float* W; int kbeg, kspan;
    if (slice < ZS1) { A = xcat;        W = Wih; kbeg = slice * ((EM + E) / ZS1); kspan = (EM + E) / ZS1; }
    else             { A = xcat + HOFF; W = Whh; kbeg = (slice - ZS1) * (D / ZS2); kspan = D / ZS2; }
    int kend = kbeg + kspan;
    float* C = zpart + (size_t)slice * B * 4 * D;
    int n0 = blockIdx.x * 64;
    int t = threadIdx.x;
    int tx = t & 15, ty = t >> 4;
    int arow = t >> 2, ak4 = (t & 3) * 4;
    int bk = t >> 4, bc4 = (t & 15) * 4;
    float4 pav = *(const float4*)&A[(size_t)arow * XC + kbeg + ak4];
    float4 pbv = *(const float4*)&W[(size_t)(kbeg + bk) * (4 * D) + n0 + bc4];
    float acc[4][4] = {};
    for (int k0 = kbeg; k0 < kend; k0 += 16) {
        As[ak4 + 0][arow] = pav.x; As[ak4 + 1][arow] = pav.y;
        As[ak4 + 2][arow] = pav.z; As[ak4 + 3][arow] = pav.w;
        *(float4*)&Bs[bk][bc4] = pbv;
        __syncthreads();
        if (k0 + 16 < kend) {
            pav = *(const float4*)&A[(size_t)arow * XC + k0 + 16 + ak4];
            pbv = *(const float4*)&W[(size_t)(k0 + 16 + bk) * (4 * D) + n0 + bc4];
        }
#pragma unroll
        for (int kk = 0; kk < 16; ++kk) {
            float4 a4 = *(const float4*)&As[kk][ty * 4];
            float4 b4 = *(const float4*)&Bs[kk][tx * 4];
            acc[0][0] += a4.x * b4.x; acc[0][1] += a4.x * b4.y; acc[0][2] += a4.x * b4.z; acc[0][3] += a4.x * b4.w;
            acc[1][0] += a4.y * b4.x; acc[1][1] += a4.y * b4.y; acc[1][2] += a4.y * b4.z; acc[1][3] += a4.y * b4.w;
            acc[2][0] += a4.z * b4.x; acc[2][1] += a4.z * b4.y; acc[2][2] += a4.z * b4.z; acc[2][3] += a4.z * b4.w;
            acc[3][0] += a4.w * b4.x; acc[3][1] += a4.w * b4.y; acc[3][2] += a4.w * b4.z; acc[3][3] += a4.w * b4.w;
        }
        __syncthreads();
    }
#pragma unroll
    for (int i = 0; i < 4; ++i) {
        int row = ty * 4 + i;
#pragma unroll
        for (int j = 0; j < 4; ++j)
            C[(size_t)row * (4 * D) + n0 + tx * 4 + j] = acc[i][j];
    }
}

// ---------------- LSTM float4: reduce 12 zpart slices + gates; h -> xcat ----------------
__global__ __launch_bounds__(256) void k_lstm(const float* __restrict__ zpart,
                                              const float* __restrict__ blstm,
                                              float* __restrict__ c,
                                              float* __restrict__ xcat) {
    int i4 = blockIdx.x * 256 + threadIdx.x;  // 8192 total (B*D/4)
    int b = i4 >> 7;
    int d4 = (i4 & 127) << 2;
    const float* zp = zpart + (size_t)b * (4 * D);
    float4 zi = *(const float4*)&blstm[d4];
    float4 zf = *(const float4*)&blstm[D + d4];
    float4 zg = *(const float4*)&blstm[2 * D + d4];
    float4 zo = *(const float4*)&blstm[3 * D + d4];
#pragma unroll
    for (int s = 0; s < ZS1 + ZS2; ++s) {
        const float* p = zp + (size_t)s * B * 4 * D;
        float4 a = *(const float4*)&p[d4];
        float4 bb = *(const float4*)&p[D + d4];
        float4 g = *(const float4*)&p[2 * D + d4];
        float4 o = *(const float4*)&p[3 * D + d4];
        zi.x += a.x; zi.y += a.y; zi.z += a.z; zi.w += a.w;
        zf.x += bb.x; zf.y += bb.y; zf.z += bb.z; zf.w += bb.w;
        zg.x += g.x; zg.y += g.y; zg.z += g.z; zg.w += g.w;
        zo.x += o.x; zo.y += o.y; zo.z += o.z; zo.w += o.w;
    }
    float4 cv = *(float4*)&c[(size_t)b * D + d4];
    float4 hv;
#define LSTM1(comp) { \
        float cn = sigmoidf_(zf.comp) * cv.comp + sigmoidf_(zi.comp) * tanhf(zg.comp); \
        cv.comp = cn; hv.comp = sigmoidf_(zo.comp) * tanhf(cn); }
    LSTM1(x) LSTM1(y) LSTM1(z) LSTM1(w)
#undef LSTM1
    *(float4*)&c[(size_t)b * D + d4] = cv;
    *(float4*)&xcat[(size_t)b * XC + HOFF + d4] = hv;
}

// ---------------- preds split-K: predsp[sl][b][V] (prefetched) ----------------
__global__ __launch_bounds__(256) void k_preds(const float* __restrict__ xcat,
                                               const float* __restrict__ Wfc,
                                               const float* __restrict__ bfc,
                                               float* __restrict__ predsp) {
    __shared__ float As[16][68];
    __shared__ float Bs[16][64];
    int slice = blockIdx.y;
    int kbeg = slice * (D / PS), kend = kbeg + D / PS;
    float* preds = predsp + (size_t)slice * B * V;
    const float* bias = (slice == 0) ? bfc : nullptr;
    const float* A = xcat + HOFF;
    int n0 = blockIdx.x * 64;
    int t = threadIdx.x;
    int tx = t & 15, ty = t >> 4;
    int arow = t >> 2, ak4 = (t & 3) * 4;
    int bk = t >> 4, bc4 = (t & 15) * 4;
    float4 pav = *(const float4*)&A[(size_t)arow * XC + kbeg + ak4];
    float4 pbv = ldg4_guard(&Wfc[(size_t)(kbeg + bk) * V], n0 + bc4, V);
    float acc[4][4] = {};
    for (int k0 = kbeg; k0 < kend; k0 += 16) {
        As[ak4 + 0][arow] = pav.x; As[ak4 + 1][arow] = pav.y;
        As[ak4 + 2][arow] = pav.z; As[ak4 + 3][arow] = pav.w;
        *(float4*)&Bs[bk][bc4] = pbv;
        __syncthreads();
        if (k0 + 16 < kend) {
            pav = *(const float4*)&A[(size_t)arow * XC + k0 + 16 + ak4];
            pbv = ldg4_guard(&Wfc[(size_t)(k0 + 16 + bk) * V], n0 + bc4, V);
        }
#pragma unroll
        for (int kk = 0; kk < 16; ++kk) {
            float4 a4 = *(const float4*)&As[kk][ty * 4];
            float4 b4 = *(const float4*)&Bs[kk][tx * 4];
            acc[0][0] += a4.x * b4.x; acc[0][1] += a4.x * b4.y; acc[0][2] += a4.x * b4.z; acc[0][3] += a4.x * b4.w;
            acc[1][0] += a4.y * b4.x; acc[1][1] += a4.y * b4.y; acc[1][2] += a4.y * b4.z; acc[1][3] += a4.y * b4.w;
            acc[2][0] += a4.z * b4.x; acc[2][1] += a4.z * b4.y; acc[2][2] += a4.z * b4.z; acc[2][3] += a4.z * b4.w;
            acc[3][0] += a4.w * b4.x; acc[3][1] += a4.w * b4.y; acc[3][2] += a4.w * b4.z; acc[3][3] += a4.w * b4.w;
        }
        __syncthreads();
    }
#pragma unroll
    for (int i = 0; i < 4; ++i) {
        int row = ty * 4 + i;
#pragma unroll
        for (int j = 0; j < 4; ++j) {
            int col = n0 + tx * 4 + j;
            if (col < V) {
                float v = acc[i][j];
                if (bias) v += bias[col];
                preds[(size_t)row * V + col] = v;
            }
        }
    }
}

// ---------------- argmax over V (sums PS partials) -> token + next inp ----------------
__global__ __launch_bounds__(256) void k_argmax(const float* __restrict__ predsp,
                                                const float* __restrict__ emb,
                                                float* __restrict__ xcat,
                                                int* __restrict__ out,
                                                int step) {
    __shared__ float vals[256];
    __shared__ int idxs[256];
    __shared__ int pid_sh;
    int b = blockIdx.x, t = threadIdx.x;
    const float* p0 = predsp + (size_t)b * V;
    const float* p1 = predsp + (size_t)B * V + (size_t)b * V;
    float best = -INFINITY; int bi = 0;
    for (int v = t; v < V; v += 256) {
        float pv = p0[v] + p1[v];
        if (pv > best) { best = pv; bi = v; }
    }
    vals[t] = best; idxs[t] = bi; __syncthreads();
    for (int s = 128; s; s >>= 1) {
        if (t < s) {
            float ov = vals[t + s]; int oi = idxs[t + s];
            if (ov > vals[t] || (ov == vals[t] && oi < idxs[t])) { vals[t] = ov; idxs[t] = oi; }
        }
        __syncthreads();
    }
    if (t == 0) { pid_sh = idxs[0]; out[b * TSTEPS + step] = idxs[0]; }
    __syncthreads();
    int pid = pid_sh;
    for (int k = t; k < EM; k += 256) xcat[(size_t)b * XC + k] = emb[(size_t)pid * EM + k];
}

extern "C" void kernel_launch(void* const* d_in, const int* in_sizes, int n_in,
                              void* d_out, int out_size, void* d_ws, size_t ws_size,
                              hipStream_t stream) {
    const float* feat   = (const float*)d_in[0];
    const float* emb    = (const float*)d_in[1];
    const float* Wea    = (const float*)d_in[2];
    const float* Wda    = (const float*)d_in[3];
    const float* wfull  = (const float*)d_in[4];
    const float* Wih_   = (const float*)d_in[5];
    const float* bih    = (const float*)d_in[6];
    const float* Wic    = (const float*)d_in[7];
    const float* bic    = (const float*)d_in[8];
    const float* Wfb    = (const float*)d_in[9];
    const float* bfb    = (const float*)d_in[10];
    const float* Wih    = (const float*)d_in[11];
    const float* Whh    = (const float*)d_in[12];
    const float* blstm  = (const float*)d_in[13];
    const float* Wfc    = (const float*)d_in[14];
    const float* bfc    = (const float*)d_in[15];
    int* out = (int*)d_out;

    float* ws = (float*)d_ws;
    float* mean_enc = ws;                               // 131,072
    float* c        = mean_enc + (size_t)B * E;         // 32,768
    float* agp      = c + (size_t)B * D;                // 655,360
    float* scores   = agp + (size_t)AGS * B * AGW;      // 12,544
    float* xcat     = scores + (size_t)B * N;           // 196,608
    float* zpart    = xcat + (size_t)B * XC;            // 1,572,864
    float* predsp   = zpart + (size_t)(ZS1 + ZS2) * B * 4 * D;  // 1,280,000
    float* att1     = predsp + (size_t)PS * B * V;      // 6,422,528
    _Float16* Bth   = (_Float16*)(att1 + ATT1_ELEMS);   // 1,048,576 halves
    _Float16* Btl   = Bth + (size_t)AA * E;             // 1,048,576 halves
    _Float16* Ahp   = (_Float16*)(Btl + (size_t)AA * E);     // 25,690,112 halves
    _Float16* Alp   = Ahp + (size_t)M_ROWS * E;              // 25,690,112 halves

    size_t need_pack = ((size_t)((float*)(Alp + (size_t)M_ROWS * E) - ws)) * sizeof(float);
    int packed = (ws_size >= need_pack) ? 1 : 0;        // ~148 MB; deterministic per call

    // ---- one-time (per call) ----
    k_mean<<<(B * E) / 256, 256, 0, stream>>>(feat, mean_enc);
    k_init_hc<<<(B * D) / 256, 256, 0, stream>>>(mean_enc, Wih_, bih, Wic, bic, xcat, c);
    k_init_inp<<<(B * EM) / 256, 256, 0, stream>>>(emb, xcat);
    k_packB<<<(AA * E) / 256, 256, 0, stream>>>(Wea, Bth, Btl);
    if (packed) {
        k_packA<<<(M_ROWS * E / 4) / 256, 256, 0, stream>>>(feat, Ahp, Alp);
        k_att1_mfma<1><<<(M_ROWS / 64) * (AA / 128), 256, 0, stream>>>(feat, Ahp, Alp, Bth, Btl, att1);
    } else {
        k_att1_mfma<0><<<(M_ROWS / 64) * (AA / 128), 256, 0, stream>>>(feat, Ahp, Alp, Bth, Btl, att1);
    }

    for (int t = 0; t < TSTEPS; ++t) {
        k_ag<<<dim3(40, AGS), 256, 0, stream>>>(xcat, Wda, Wfb, bfb, agp);
        k_scores<<<(B * N) / 4, 256, 0, stream>>>(att1, agp, wfull, scores);
        k_awe<<<dim3(E / 512, B), 256, 0, stream>>>(scores, feat, agp, xcat);
        k_z<<<dim3((4 * D) / 64, ZS1 + ZS2), 256, 0, stream>>>(xcat, Wih, Whh, zpart);
        k_lstm<<<(B * D / 4) / 256, 256, 0, stream>>>(zpart, blstm, c, xcat);
        k_preds<<<dim3((V + 63) / 64, PS), 256, 0, stream>>>(xcat, Wfc, bfc, predsp);
        k_argmax<<<B, 256, 0, stream>>>(predsp, emb, xcat, out, t);
    }
}

// Round 14
// 2212.151 us; speedup vs baseline: 1.2174x; 1.2174x over previous
//
#include <hip/hip_runtime.h>
#include <math.h>

#define B 64
#define N 196
#define E 2048
#define D 512
#define AA 512
#define EM 512
#define V 10000
#define TSTEPS 20
#define XC 3072          // xcat: [inp(512) | awe(2048) | h(512)] contiguous
#define HOFF 2560        // h slot offset in xcat
#define AGW 2560         // ag row: [att2(512) | gate(2048)]
#define AGS 4            // split-K slices for att2|gate
#define ZS1 8            // split-K slices for W_ih
#define ZS2 4            // split-K slices for W_hh
#define PS 2             // split-K slices for preds
#define ATT1_ELEMS ((size_t)B * N * AA)   // 6422528
#define M_ROWS (B * N)                    // 12544
#define KT (E / 16)                       // 128 k-tiles

typedef _Float16 f16x4 __attribute__((ext_vector_type(4)));
typedef float f32x4v __attribute__((ext_vector_type(4)));

__device__ __forceinline__ float sigmoidf_(float x) { return 1.0f / (1.0f + expf(-x)); }

__device__ __forceinline__ float4 ldg4_guard(const float* __restrict__ wp, int n, int Nn) {
    if (n + 3 < Nn) return *(const float4*)&wp[n];
    float4 bv;
    bv.x = (n     < Nn) ? wp[n]     : 0.f;
    bv.y = (n + 1 < Nn) ? wp[n + 1] : 0.f;
    bv.z = (n + 2 < Nn) ? wp[n + 2] : 0.f;
    bv.w = (n + 3 < Nn) ? wp[n + 3] : 0.f;
    return bv;
}

__device__ __forceinline__ void split4(float4 v, f16x4& h, f16x4& lo) {
    h[0] = (_Float16)v.x; lo[0] = (_Float16)(v.x - (float)h[0]);
    h[1] = (_Float16)v.y; lo[1] = (_Float16)(v.y - (float)h[1]);
    h[2] = (_Float16)v.z; lo[2] = (_Float16)(v.z - (float)h[2]);
    h[3] = (_Float16)v.w; lo[3] = (_Float16)(v.w - (float)h[3]);
}

// ---------------- mean over N ----------------
__global__ __launch_bounds__(256) void k_mean(const float* __restrict__ feat,
                                              float* __restrict__ mean_enc) {
    int i = blockIdx.x * 256 + threadIdx.x;
    int b = i >> 11, e = i & (E - 1);
    const float* p = feat + (size_t)b * N * E + e;
    float s = 0.f;
    for (int n = 0; n < N; ++n) s += p[(size_t)n * E];
    mean_enc[i] = s * (1.0f / (float)N);
}

// ---------------- h,c init; h written into xcat h-slot ----------------
__global__ __launch_bounds__(256) void k_init_hc(const float* __restrict__ me,
                                                 const float* __restrict__ Wh, const float* __restrict__ bh,
                                                 const float* __restrict__ Wc, const float* __restrict__ bc,
                                                 float* __restrict__ xcat, float* __restrict__ c) {
    int i = blockIdx.x * 256 + threadIdx.x;
    int b = i >> 9, d = i & (D - 1);
    const float* m = me + (size_t)b * E;
    float ha = bh[d], ca = bc[d];
    for (int e = 0; e < E; ++e) {
        float mv = m[e];
        ha += mv * Wh[(size_t)e * D + d];
        ca += mv * Wc[(size_t)e * D + d];
    }
    xcat[(size_t)b * XC + HOFF + d] = ha;
    c[i] = ca;
}

// ---------------- inp = embedding[1] into xcat ----------------
__global__ __launch_bounds__(256) void k_init_inp(const float* __restrict__ emb,
                                                  float* __restrict__ xcat) {
    int i = blockIdx.x * 256 + threadIdx.x;   // 32768
    int b = i >> 9, k = i & (EM - 1);
    xcat[(size_t)b * XC + k] = emb[EM + k];
}

// ---------------- pack A (feat) into MFMA-frag order, f16 hi/lo ----------------
// Ah2[((rt*KT + kt)*64 + l)*4 + j] = feat[rt*16 + (l&15)][kt*16 + 4*(l>>4) + j]
// so the GEMM's per-wave frag load is base + l*8B  ->  one coalesced 512B transaction.
__global__ __launch_bounds__(256) void k_packA2(const float* __restrict__ feat,
                                                _Float16* __restrict__ Ah2,
                                                _Float16* __restrict__ Al2) {
    int i = blockIdx.x * 256 + threadIdx.x;   // 784*128*64 = 6,422,528
    int l = i & 63, kt = (i >> 6) & (KT - 1), rt = i >> 13;
    int lr = l & 15, lk = l >> 4;
    float4 v = *(const float4*)&feat[(size_t)(rt * 16 + lr) * E + kt * 16 + 4 * lk];
    f16x4 h, lo;
    split4(v, h, lo);
    *(f16x4*)&Ah2[(size_t)i * 4] = h;
    *(f16x4*)&Al2[(size_t)i * 4] = lo;
}

// ---------------- pack B (W_enc_att) into MFMA-frag order, f16 hi/lo ----------------
// Bh2[((ct*KT + kt)*64 + l)*4 + j] = Wea[(kt*16 + 4*(l>>4) + j)*AA + ct*16 + (l&15)]
__global__ __launch_bounds__(256) void k_packB2(const float* __restrict__ Wea,
                                                _Float16* __restrict__ Bh2,
                                                _Float16* __restrict__ Bl2) {
    int i = blockIdx.x * 256 + threadIdx.x;   // 32*128*64 = 262,144
    int l = i & 63, kt = (i >> 6) & (KT - 1), ct = i >> 13;
    int lr = l & 15, lk = l >> 4;
    int k = kt * 16 + 4 * lk, n = ct * 16 + lr;
    f16x4 h, lo;
    float4 v;
    v.x = Wea[(size_t)(k + 0) * AA + n];
    v.y = Wea[(size_t)(k + 1) * AA + n];
    v.z = Wea[(size_t)(k + 2) * AA + n];
    v.w = Wea[(size_t)(k + 3) * AA + n];
    split4(v, h, lo);
    *(f16x4*)&Bh2[(size_t)i * 4] = h;
    *(f16x4*)&Bl2[(size_t)i * 4] = lo;
}

// ---------------- att1 via MFMA f16 hi/lo on frag-order packed inputs ----------------
// C = Ahi*Bhi + Ahi*Blo + Alo*Bhi (layouts HW-verified r12, absmax 0; pack is the exact
// inverse of the verified read pattern). All loads 512B-coalesced. No LDS, no barriers.
// Grid 784 = 8 XCD chunks x 98 (4 col-tiles of one A-row-tile land on one XCD's L2).
__global__ __launch_bounds__(256) void k_att1_mfma(const _Float16* __restrict__ Ah2,
                                                   const _Float16* __restrict__ Al2,
                                                   const _Float16* __restrict__ Bh2,
                                                   const _Float16* __restrict__ Bl2,
                                                   float* __restrict__ Cm) {
    int bid = blockIdx.x;                  // 784 = 8 * 98
    int wg = (bid & 7) * 98 + (bid >> 3);  // bijective
    int xt = wg >> 2, yc = wg & 3;         // xt: 64-row tile 0..195, yc: 128-col tile 0..3
    int w = threadIdx.x >> 6, l = threadIdx.x & 63;
    int wr = w >> 1, wc = w & 1;
    int row0 = xt * 64 + wr * 32;
    int col0 = yc * 128 + wc * 64;
    int lr = l & 15, lk = l >> 4;
    int rt0 = xt * 4 + wr * 2, rt1 = rt0 + 1;
    int ct0 = yc * 8 + wc * 4;             // + ni
    // frag pointers (advance by 64 f16x4 per kt)
    const f16x4* a0h = (const f16x4*)Ah2 + (size_t)rt0 * KT * 64 + l;
    const f16x4* a0l = (const f16x4*)Al2 + (size_t)rt0 * KT * 64 + l;
    const f16x4* a1h = (const f16x4*)Ah2 + (size_t)rt1 * KT * 64 + l;
    const f16x4* a1l = (const f16x4*)Al2 + (size_t)rt1 * KT * 64 + l;
    const f16x4* bhp[4]; const f16x4* blp[4];
#pragma unroll
    for (int ni = 0; ni < 4; ++ni) {
        bhp[ni] = (const f16x4*)Bh2 + (size_t)(ct0 + ni) * KT * 64 + l;
        blp[ni] = (const f16x4*)Bl2 + (size_t)(ct0 + ni) * KT * 64 + l;
    }
    f32x4v acc[2][4] = {};
    f16x4 ah0, al0, ah1, al1, bh[4], bl[4];
    f16x4 nah0, nal0, nah1, nal1, nbh[4], nbl[4];

#define LOAD_FRAGS(kt, H0, L0, H1, L1, BH, BL)          \
    {                                                   \
        int off = (kt) * 64;                            \
        H0 = a0h[off]; L0 = a0l[off];                   \
        H1 = a1h[off]; L1 = a1l[off];                   \
        _Pragma("unroll")                               \
        for (int ni = 0; ni < 4; ++ni) {                \
            BH[ni] = bhp[ni][off];                      \
            BL[ni] = blp[ni][off];                      \
        }                                               \
    }

    LOAD_FRAGS(0, ah0, al0, ah1, al1, bh, bl)
    for (int kt = 0; kt < KT; ++kt) {
        if (kt + 1 < KT) {                 // prefetch next k-tile (in flight over MFMAs)
            LOAD_FRAGS(kt + 1, nah0, nal0, nah1, nal1, nbh, nbl)
        }
#pragma unroll
        for (int ni = 0; ni < 4; ++ni) {
            acc[0][ni] = __builtin_amdgcn_mfma_f32_16x16x16f16(ah0, bh[ni], acc[0][ni], 0, 0, 0);
            acc[0][ni] = __builtin_amdgcn_mfma_f32_16x16x16f16(ah0, bl[ni], acc[0][ni], 0, 0, 0);
            acc[0][ni] = __builtin_amdgcn_mfma_f32_16x16x16f16(al0, bh[ni], acc[0][ni], 0, 0, 0);
            acc[1][ni] = __builtin_amdgcn_mfma_f32_16x16x16f16(ah1, bh[ni], acc[1][ni], 0, 0, 0);
            acc[1][ni] = __builtin_amdgcn_mfma_f32_16x16x16f16(ah1, bl[ni], acc[1][ni], 0, 0, 0);
            acc[1][ni] = __builtin_amdgcn_mfma_f32_16x16x16f16(al1, bh[ni], acc[1][ni], 0, 0, 0);
        }
        ah0 = nah0; al0 = nal0; ah1 = nah1; al1 = nal1;
#pragma unroll
        for (int ni = 0; ni < 4; ++ni) { bh[ni] = nbh[ni]; bl[ni] = nbl[ni]; }
    }
#undef LOAD_FRAGS
#pragma unroll
    for (int mi = 0; mi < 2; ++mi)
#pragma unroll
        for (int ni = 0; ni < 4; ++ni)
#pragma unroll
            for (int r = 0; r < 4; ++r)
                Cm[(size_t)(row0 + 16 * mi + lk * 4 + r) * AA + col0 + 16 * ni + lr] = acc[mi][ni][r];
}

// ---------------- att2|gate split-K: agp[sl][b][2560] (register-prefetched) ----------------
__global__ __launch_bounds__(256) void k_ag(const float* __restrict__ xcat,
                                            const float* __restrict__ Wda,
                                            const float* __restrict__ Wfb,
                                            const float* __restrict__ bfb,
                                            float* __restrict__ agp) {
    __shared__ float As[16][68];
    __shared__ float Bs[16][64];
    int tile = blockIdx.x, slice = blockIdx.y;
    const float* W; const float* bias = nullptr; int ldw, n0, co;
    if (tile < 8) { W = Wda; ldw = AA; n0 = tile * 64;       co = n0; }
    else          { W = Wfb; ldw = E;  n0 = (tile - 8) * 64; co = AA + n0;
                    if (slice == 0) bias = bfb; }
    float* ag = agp + (size_t)slice * B * AGW;
    int kbeg = slice * (D / AGS), kend = kbeg + D / AGS;
    const float* A = xcat + HOFF;
    int t = threadIdx.x;
    int tx = t & 15, ty = t >> 4;
    int arow = t >> 2, ak4 = (t & 3) * 4;
    int bk = t >> 4, bc4 = (t & 15) * 4;
    float4 pav = *(const float4*)&A[(size_t)arow * XC + kbeg + ak4];
    float4 pbv = *(const float4*)&W[(size_t)(kbeg + bk) * ldw + n0 + bc4];
    float acc[4][4] = {};
    for (int k0 = kbeg; k0 < kend; k0 += 16) {
        As[ak4 + 0][arow] = pav.x; As[ak4 + 1][arow] = pav.y;
        As[ak4 + 2][arow] = pav.z; As[ak4 + 3][arow] = pav.w;
        *(float4*)&Bs[bk][bc4] = pbv;
        __syncthreads();
        if (k0 + 16 < kend) {
            pav = *(const float4*)&A[(size_t)arow * XC + k0 + 16 + ak4];
            pbv = *(const float4*)&W[(size_t)(k0 + 16 + bk) * ldw + n0 + bc4];
        }
#pragma unroll
        for (int kk = 0; kk < 16; ++kk) {
            float4 a4 = *(const float4*)&As[kk][ty * 4];
            float4 b4 = *(const float4*)&Bs[kk][tx * 4];
            acc[0][0] += a4.x * b4.x; acc[0][1] += a4.x * b4.y; acc[0][2] += a4.x * b4.z; acc[0][3] += a4.x * b4.w;
            acc[1][0] += a4.y * b4.x; acc[1][1] += a4.y * b4.y; acc[1][2] += a4.y * b4.z; acc[1][3] += a4.y * b4.w;
            acc[2][0] += a4.z * b4.x; acc[2][1] += a4.z * b4.y; acc[2][2] += a4.z * b4.z; acc[2][3] += a4.z * b4.w;
            acc[3][0] += a4.w * b4.x; acc[3][1] += a4.w * b4.y; acc[3][2] += a4.w * b4.z; acc[3][3] += a4.w * b4.w;
        }
        __syncthreads();
    }
#pragma unroll
    for (int i = 0; i < 4; ++i) {
        int row = ty * 4 + i;
#pragma unroll
        for (int j = 0; j < 4; ++j) {
            float v = acc[i][j];
            if (bias) v += bias[n0 + tx * 4 + j];
            ag[(size_t)row * AGW + co + tx * 4 + j] = v;
        }
    }
}

// ---------------- scores: wave per (b,n) row, float4; sums AGS att2 partials ----------------
__global__ __launch_bounds__(256) void k_scores(const float* __restrict__ att1,
                                                const float* __restrict__ agp,
                                                const float* __restrict__ wfull,
                                                float* __restrict__ scores) {
    int wid = threadIdx.x >> 6, lane = threadIdx.x & 63;
    int bn = blockIdx.x * 4 + wid;            // 12544 rows
    int b = bn / N;
    const float* a1 = att1 + (size_t)bn * AA;
    const float* a2 = agp + (size_t)b * AGW;
    const size_t SL = (size_t)B * AGW;
    float s = 0.f;
#pragma unroll
    for (int i = 0; i < AA / 256; ++i) {
        int a = i * 256 + lane * 4;
        float4 v  = *(const float4*)&a1[a];
        float4 p0 = *(const float4*)&a2[a];
        float4 p1 = *(const float4*)&a2[SL + a];
        float4 p2 = *(const float4*)&a2[2 * SL + a];
        float4 p3 = *(const float4*)&a2[3 * SL + a];
        float4 wf = *(const float4*)&wfull[a];
        s += fmaxf(v.x + p0.x + p1.x + p2.x + p3.x, 0.f) * wf.x;
        s += fmaxf(v.y + p0.y + p1.y + p2.y + p3.y, 0.f) * wf.y;
        s += fmaxf(v.z + p0.z + p1.z + p2.z + p3.z, 0.f) * wf.z;
        s += fmaxf(v.w + p0.w + p1.w + p2.w + p3.w, 0.f) * wf.w;
    }
    for (int off = 32; off; off >>= 1) s += __shfl_down(s, off);
    if (lane == 0) scores[bn] = s;
}

// ---------------- awe: in-block softmax + float2 weighted sum + gate ----------------
__global__ __launch_bounds__(256) void k_awe(const float* __restrict__ scores,
                                             const float* __restrict__ feat,
                                             const float* __restrict__ agp,
                                             float* __restrict__ xcat) {
    __shared__ float al[N];
    __shared__ float red[256];
    int b = blockIdx.y, ch = blockIdx.x, t = threadIdx.x;
    float v = (t < N) ? scores[b * N + t] : -INFINITY;
    red[t] = v; __syncthreads();
    for (int s = 128; s; s >>= 1) { if (t < s) red[t] = fmaxf(red[t], red[t + s]); __syncthreads(); }
    float mx = red[0]; __syncthreads();
    float e = (t < N) ? expf(v - mx) : 0.f;
    red[t] = e; __syncthreads();
    for (int s = 128; s; s >>= 1) { if (t < s) red[t] += red[t + s]; __syncthreads(); }
    float inv = 1.0f / red[0];
    if (t < N) al[t] = e * inv;
    __syncthreads();
    int e0 = ch * 512 + t * 2;
    const float* f = feat + (size_t)b * N * E + e0;
    float sx = 0.f, sy = 0.f;
    for (int n = 0; n < N; n += 2) {     // N even: no tail
        float a0 = al[n], a1v = al[n + 1];
        float2 f0 = *(const float2*)f;
        float2 f1 = *(const float2*)(f + E);
        sx += a0 * f0.x + a1v * f1.x;
        sy += a0 * f0.y + a1v * f1.y;
        f += (size_t)2 * E;
    }
    const float* gp = agp + (size_t)b * AGW + AA + e0;
    const size_t SL = (size_t)B * AGW;
    float2 g0 = *(const float2*)&gp[0];
    float2 g1 = *(const float2*)&gp[SL];
    float2 g2 = *(const float2*)&gp[2 * SL];
    float2 g3 = *(const float2*)&gp[3 * SL];
    float2 o;
    o.x = sx * sigmoidf_(g0.x + g1.x + g2.x + g3.x);
    o.y = sy * sigmoidf_(g0.y + g1.y + g2.y + g3.y);
    *(float2*)&xcat[(size_t)b * XC + EM + e0] = o;
}

// ---------------- z partials: one launch, 12 slices (8 ih + 4 hh), prefetched ----------------
__global__ __launch_bounds__(256) void k_z(const float* __restrict__ xcat,
                                           const float* __restrict__ Wih,
                                           const float* __restrict__ Whh,
                                           float* __restrict__ zpart) {
    __shared__ float As[16][68];
    __shared__ float Bs[16][64];
    int slice = blockIdx.y;
    const float* A; const float* W; int kbeg, kspan;
    if (slice < ZS1) { A = xcat;        W = Wih; kbeg = slice * ((EM + E) / ZS1); kspan = (EM + E) / ZS1; }
    else             { A = xcat + HOFF; W = Whh; kbeg = (slice - ZS1) * (D / ZS2); kspan = D / ZS2; }
    int kend = kbeg + kspan;
    float* C = zpart + (size_t)slice * B * 4 * D;
    int n0 = blockIdx.x * 64;
    int t = threadIdx.x;
    int tx = t & 15, ty = t >> 4;
    int arow = t >> 2, ak4 = (t & 3) * 4;
    int bk = t >> 4, bc4 = (t & 15) * 4;
    float4 pav = *(const float4*)&A[(size_t)arow * XC + kbeg + ak4];
    float4 pbv = *(const float4*)&W[(size_t)(kbeg + bk) * (4 * D) + n0 + bc4];
    float acc[4][4] = {};
    for (int k0 = kbeg; k0 < kend; k0 += 16) {
        As[ak4 + 0][arow] = pav.x; As[ak4 + 1][arow] = pav.y;
        As[ak4 + 2][arow] = pav.z; As[ak4 + 3][arow] = pav.w;
        *(float4*)&Bs[bk][bc4] = pbv;
        __syncthreads();
        if (k0 + 16 < kend) {
            pav = *(const float4*)&A[(size_t)arow * XC + k0 + 16 + ak4];
            pbv = *(const float4*)&W[(size_t)(k0 + 16 + bk) * (4 * D) + n0 + bc4];
        }
#pragma unroll
        for (int kk = 0; kk < 16; ++kk) {
            float4 a4 = *(const float4*)&As[kk][ty * 4];
            float4 b4 = *(const float4*)&Bs[kk][tx * 4];
            acc[0][0] += a4.x * b4.x; acc[0][1] += a4.x * b4.y; acc[0][2] += a4.x * b4.z; acc[0][3] += a4.x * b4.w;
            acc[1][0] += a4.y * b4.x; acc[1][1] += a4.y * b4.y; acc[1][2] += a4.y * b4.z; acc[1][3] += a4.y * b4.w;
            acc[2][0] += a4.z * b4.x; acc[2][1] += a4.z * b4.y; acc[2][2] += a4.z * b4.z; acc[2][3] += a4.z * b4.w;
            acc[3][0] += a4.w * b4.x; acc[3][1] += a4.w * b4.y; acc[3][2] += a4.w * b4.z; acc[3][3] += a4.w * b4.w;
        }
        __syncthreads();
    }
#pragma unroll
    for (int i = 0; i < 4; ++i) {
        int row = ty * 4 + i;
#pragma unroll
        for (int j = 0; j < 4; ++j)
            C[(size_t)row * (4 * D) + n0 + tx * 4 + j] = acc[i][j];
    }
}

// ---------------- LSTM float4: reduce 12 zpart slices + gates; h -> xcat ----------------
__global__ __launch_bounds__(256) void k_lstm(const float* __restrict__ zpart,
                                              const float* __restrict__ blstm,
                                              float* __restrict__ c,
                                              float* __restrict__ xcat) {
    int i4 = blockIdx.x * 256 + threadIdx.x;  // 8192 total (B*D/4)
    int b = i4 >> 7;
    int d4 = (i4 & 127) << 2;
    const float* zp = zpart + (size_t)b * (4 * D);
    float4 zi = *(const float4*)&blstm[d4];
    float4 zf = *(const float4*)&blstm[D + d4];
    float4 zg = *(const float4*)&blstm[2 * D + d4];
    float4 zo = *(const float4*)&blstm[3 * D + d4];
#pragma unroll
    for (int s = 0; s < ZS1 + ZS2; ++s) {
        const float* p = zp + (size_t)s * B * 4 * D;
        float4 a = *(const float4*)&p[d4];
        float4 bb = *(const float4*)&p[D + d4];
        float4 g = *(const float4*)&p[2 * D + d4];
        float4 o = *(const float4*)&p[3 * D + d4];
        zi.x += a.x; zi.y += a.y; zi.z += a.z; zi.w += a.w;
        zf.x += bb.x; zf.y += bb.y; zf.z += bb.z; zf.w += bb.w;
        zg.x += g.x; zg.y += g.y; zg.z += g.z; zg.w += g.w;
        zo.x += o.x; zo.y += o.y; zo.z += o.z; zo.w += o.w;
    }
    float4 cv = *(float4*)&c[(size_t)b * D + d4];
    float4 hv;
#define LSTM1(comp) { \
        float cn = sigmoidf_(zf.comp) * cv.comp + sigmoidf_(zi.comp) * tanhf(zg.comp); \
        cv.comp = cn; hv.comp = sigmoidf_(zo.comp) * tanhf(cn); }
    LSTM1(x) LSTM1(y) LSTM1(z) LSTM1(w)
#undef LSTM1
    *(float4*)&c[(size_t)b * D + d4] = cv;
    *(float4*)&xcat[(size_t)b * XC + HOFF + d4] = hv;
}

// ---------------- preds split-K: predsp[sl][b][V] (prefetched) ----------------
__global__ __launch_bounds__(256) void k_preds(const float* __restrict__ xcat,
                                               const float* __restrict__ Wfc,
                                               const float* __restrict__ bfc,
                                               float* __restrict__ predsp) {
    __shared__ float As[16][68];
    __shared__ float Bs[16][64];
    int slice = blockIdx.y;
    int kbeg = slice * (D / PS), kend = kbeg + D / PS;
    float* preds = predsp + (size_t)slice * B * V;
    const float* bias = (slice == 0) ? bfc : nullptr;
    const float* A = xcat + HOFF;
    int n0 = blockIdx.x * 64;
    int t = threadIdx.x;
    int tx = t & 15, ty = t >> 4;
    int arow = t >> 2, ak4 = (t & 3) * 4;
    int bk = t >> 4, bc4 = (t & 15) * 4;
    float4 pav = *(const float4*)&A[(size_t)arow * XC + kbeg + ak4];
    float4 pbv = ldg4_guard(&Wfc[(size_t)(kbeg + bk) * V], n0 + bc4, V);
    float acc[4][4] = {};
    for (int k0 = kbeg; k0 < kend; k0 += 16) {
        As[ak4 + 0][arow] = pav.x; As[ak4 + 1][arow] = pav.y;
        As[ak4 + 2][arow] = pav.z; As[ak4 + 3][arow] = pav.w;
        *(float4*)&Bs[bk][bc4] = pbv;
        __syncthreads();
        if (k0 + 16 < kend) {
            pav = *(const float4*)&A[(size_t)arow * XC + k0 + 16 + ak4];
            pbv = ldg4_guard(&Wfc[(size_t)(k0 + 16 + bk) * V], n0 + bc4, V);
        }
#pragma unroll
        for (int kk = 0; kk < 16; ++kk) {
            float4 a4 = *(const float4*)&As[kk][ty * 4];
            float4 b4 = *(const float4*)&Bs[kk][tx * 4];
            acc[0][0] += a4.x * b4.x; acc[0][1] += a4.x * b4.y; acc[0][2] += a4.x * b4.z; acc[0][3] += a4.x * b4.w;
            acc[1][0] += a4.y * b4.x; acc[1][1] += a4.y * b4.y; acc[1][2] += a4.y * b4.z; acc[1][3] += a4.y * b4.w;
            acc[2][0] += a4.z * b4.x; acc[2][1] += a4.z * b4.y; acc[2][2] += a4.z * b4.z; acc[2][3] += a4.z * b4.w;
            acc[3][0] += a4.w * b4.x; acc[3][1] += a4.w * b4.y; acc[3][2] += a4.w * b4.z; acc[3][3] += a4.w * b4.w;
        }
        __syncthreads();
    }
#pragma unroll
    for (int i = 0; i < 4; ++i) {
        int row = ty * 4 + i;
#pragma unroll
        for (int j = 0; j < 4; ++j) {
            int col = n0 + tx * 4 + j;
            if (col < V) {
                float v = acc[i][j];
                if (bias) v += bias[col];
                preds[(size_t)row * V + col] = v;
            }
        }
    }
}

// ---------------- argmax over V (sums PS partials) -> token + next inp ----------------
__global__ __launch_bounds__(256) void k_argmax(const float* __restrict__ predsp,
                                                const float* __restrict__ emb,
                                                float* __restrict__ xcat,
                                                int* __restrict__ out,
                                                int step) {
    __shared__ float vals[256];
    __shared__ int idxs[256];
    __shared__ int pid_sh;
    int b = blockIdx.x, t = threadIdx.x;
    const float* p0 = predsp + (size_t)b * V;
    const float* p1 = predsp + (size_t)B * V + (size_t)b * V;
    float best = -INFINITY; int bi = 0;
    for (int v = t; v < V; v += 256) {
        float pv = p0[v] + p1[v];
        if (pv > best) { best = pv; bi = v; }
    }
    vals[t] = best; idxs[t] = bi; __syncthreads();
    for (int s = 128; s; s >>= 1) {
        if (t < s) {
            float ov = vals[t + s]; int oi = idxs[t + s];
            if (ov > vals[t] || (ov == vals[t] && oi < idxs[t])) { vals[t] = ov; idxs[t] = oi; }
        }
        __syncthreads();
    }
    if (t == 0) { pid_sh = idxs[0]; out[b * TSTEPS + step] = idxs[0]; }
    __syncthreads();
    int pid = pid_sh;
    for (int k = t; k < EM; k += 256) xcat[(size_t)b * XC + k] = emb[(size_t)pid * EM + k];
}

extern "C" void kernel_launch(void* const* d_in, const int* in_sizes, int n_in,
                              void* d_out, int out_size, void* d_ws, size_t ws_size,
                              hipStream_t stream) {
    const float* feat   = (const float*)d_in[0];
    const float* emb    = (const float*)d_in[1];
    const float* Wea    = (const float*)d_in[2];
    const float* Wda    = (const float*)d_in[3];
    const float* wfull  = (const float*)d_in[4];
    const float* Wih_   = (const float*)d_in[5];
    const float* bih    = (const float*)d_in[6];
    const float* Wic    = (const float*)d_in[7];
    const float* bic    = (const float*)d_in[8];
    const float* Wfb    = (const float*)d_in[9];
    const float* bfb    = (const float*)d_in[10];
    const float* Wih    = (const float*)d_in[11];
    const float* Whh    = (const float*)d_in[12];
    const float* blstm  = (const float*)d_in[13];
    const float* Wfc    = (const float*)d_in[14];
    const float* bfc    = (const float*)d_in[15];
    int* out = (int*)d_out;

    float* ws = (float*)d_ws;
    float* mean_enc = ws;                               // 131,072
    float* c        = mean_enc + (size_t)B * E;         // 32,768
    float* agp      = c + (size_t)B * D;                // 655,360
    float* scores   = agp + (size_t)AGS * B * AGW;      // 12,544
    float* xcat     = scores + (size_t)B * N;           // 196,608
    float* zpart    = xcat + (size_t)B * XC;            // 1,572,864
    float* predsp   = zpart + (size_t)(ZS1 + ZS2) * B * 4 * D;  // 1,280,000
    float* att1     = predsp + (size_t)PS * B * V;      // 6,422,528
    _Float16* Bh2   = (_Float16*)(att1 + ATT1_ELEMS);   // 1,048,576 halves
    _Float16* Bl2   = Bh2 + (size_t)AA * E;             // 1,048,576 halves
    _Float16* Ah2   = (_Float16*)(Bl2 + (size_t)AA * E);     // 25,690,112 halves
    _Float16* Al2   = Ah2 + (size_t)M_ROWS * E;              // 25,690,112 halves
    // total ~148 MB (r13's packed path ran -> ws_size is sufficient)

    // ---- one-time (per call) ----
    k_mean<<<(B * E) / 256, 256, 0, stream>>>(feat, mean_enc);
    k_init_hc<<<(B * D) / 256, 256, 0, stream>>>(mean_enc, Wih_, bih, Wic, bic, xcat, c);
    k_init_inp<<<(B * EM) / 256, 256, 0, stream>>>(emb, xcat);
    k_packB2<<<(32 * KT * 64) / 256, 256, 0, stream>>>(Wea, Bh2, Bl2);
    k_packA2<<<((M_ROWS / 16) * KT * 64) / 256, 256, 0, stream>>>(feat, Ah2, Al2);
    k_att1_mfma<<<(M_ROWS / 64) * (AA / 128), 256, 0, stream>>>(Ah2, Al2, Bh2, Bl2, att1);

    for (int t = 0; t < TSTEPS; ++t) {
        k_ag<<<dim3(40, AGS), 256, 0, stream>>>(xcat, Wda, Wfb, bfb, agp);
        k_scores<<<(B * N) / 4, 256, 0, stream>>>(att1, agp, wfull, scores);
        k_awe<<<dim3(E / 512, B), 256, 0, stream>>>(scores, feat, agp, xcat);
        k_z<<<dim3((4 * D) / 64, ZS1 + ZS2), 256, 0, stream>>>(xcat, Wih, Whh, zpart);
        k_lstm<<<(B * D / 4) / 256, 256, 0, stream>>>(zpart, blstm, c, xcat);
        k_preds<<<dim3((V + 63) / 64, PS), 256, 0, stream>>>(xcat, Wfc, bfc, predsp);
        k_argmax<<<B, 256, 0, stream>>>(predsp, emb, xcat, out, t);
    }
}